// Round 10
// baseline (608.236 us; speedup 1.0000x reference)
//
#include <hip/hip_runtime.h>
#include <hip/hip_bf16.h>
#include <cstdint>
#include <cstddef>

#define DEV __device__ __forceinline__

typedef __attribute__((ext_vector_type(8))) short short8;
typedef __attribute__((ext_vector_type(4))) float f32x4;

constexpr int Dm  = 256;
constexpr int Qn  = 128;
constexpr int Cn  = 512;
constexpr int Bn  = 4;

DEV unsigned short f2bf(float f){
  unsigned int u = __builtin_bit_cast(unsigned int, f);
  u += 0x7fffu + ((u >> 16) & 1u);
  return (unsigned short)(u >> 16);
}
DEV float bfl(unsigned int u){ return __builtin_bit_cast(float, u << 16); }
DEV float bfh(unsigned int u){ return __builtin_bit_cast(float, u & 0xffff0000u); }
DEV unsigned int pk2(float a, float b){
  return (unsigned int)f2bf(a) | ((unsigned int)f2bf(b) << 16);
}

DEV f32x4 mfma16(short8 a, short8 b, f32x4 c){
  return __builtin_amdgcn_mfma_f32_16x16x32_bf16(a, b, c, 0, 0, 0);
}

// 16x16x32 fragment load from XOR-swizzled LDS tile (rowbytes bytes/row) — for gemm_kernel
DEV short8 ldfrag(const unsigned short* buf, int rowbytes, int row0, int ks, int l){
  int r = row0 + (l & 15);
  int byte = (ks * 64 + ((l >> 4) * 16)) ^ ((r & 7) << 4);
  return *(const short8*)((const char*)buf + r * rowbytes + byte);
}

// async global->LDS, 16B/lane; LDS dest = wave-uniform base (HW adds lane*16)
DEV void gload_lds16(const void* g, void* lds){
  __builtin_amdgcn_global_load_lds(
      (const __attribute__((address_space(1))) unsigned int*)g,
      (__attribute__((address_space(3))) unsigned int*)lds, 16, 0, 0);
}

// ---------------------------------------------------------------- converts + weight packs
// pack W[f][d] into the fragment image: byte f*512 + ((d8*16) ^ ((f&15)<<4))
DEV void packw(unsigned short* dst, const float* src, int j){
  int f = j >> 8, d = j & 255;
  int d8 = d >> 3, e = d & 7;
  int byte = (d8 * 16) ^ ((f & 15) << 4);
  dst[f * 256 + (byte >> 1) + e] = f2bf(src[j]);
}

__global__ __launch_bounds__(256) void conv_all_kernel(
    const float* inw, unsigned short* inw_bf,
    const float* aow, unsigned short* aow_bf,
    const float* ow,  unsigned short* ow_bf,
    const float* f1w, unsigned short* f1w_bf,
    const float* f2w, unsigned short* f2w_bf,
    const float* m1w, unsigned short* w1pk,
    const float* m2w, unsigned short* w2pk,
    const float* vw,  unsigned short* wvpk,
    const float* memp, unsigned short* mem_bf)
{
  const int total = 196608 + 65536 + 65536 + 262144 + 262144 + 3 * 65536 + 524288;
  for (int i = blockIdx.x * 256 + threadIdx.x; i < total; i += gridDim.x * 256){
    int j = i;
    if (j < 196608){ inw_bf[j] = f2bf(inw[j]); continue; } j -= 196608;
    if (j < 65536) { aow_bf[j] = f2bf(aow[j]); continue; } j -= 65536;
    if (j < 65536) { ow_bf[j]  = f2bf(ow[j]);  continue; } j -= 65536;
    if (j < 262144){ f1w_bf[j] = f2bf(f1w[j]); continue; } j -= 262144;
    if (j < 262144){ f2w_bf[j] = f2bf(f2w[j]); continue; } j -= 262144;
    if (j < 65536) { packw(w1pk, m1w, j); continue; } j -= 65536;
    if (j < 65536) { packw(w2pk, m2w, j); continue; } j -= 65536;
    if (j < 65536) { packw(wvpk, vw, j);  continue; } j -= 65536;
    mem_bf[j] = f2bf(memp[j]);
  }
}

// ---------------------------------------------------------------- layernorm
__global__ __launch_bounds__(256) void ln_kernel(
    const float* __restrict__ in, const float* __restrict__ g, const float* __restrict__ bt,
    const float* __restrict__ addp,
    float* __restrict__ outF, unsigned short* __restrict__ outA, unsigned short* __restrict__ outB)
{
  const int r = blockIdx.x, t = threadIdx.x;
  float x = in[(size_t)r * 256 + t];
  float s = x, s2 = x * x;
  #pragma unroll
  for (int m = 1; m < 64; m <<= 1){ s += __shfl_xor(s, m, 64); s2 += __shfl_xor(s2, m, 64); }
  __shared__ float ls[8];
  int w = t >> 6, l = t & 63;
  if (l == 0){ ls[w] = s; ls[4 + w] = s2; }
  __syncthreads();
  s  = ls[0] + ls[1] + ls[2] + ls[3];
  s2 = ls[4] + ls[5] + ls[6] + ls[7];
  float mean = s * (1.f / 256.f);
  float var  = s2 * (1.f / 256.f) - mean * mean;
  float y = (x - mean) * rsqrtf(var + 1e-5f) * g[t] + bt[t];
  size_t o = (size_t)r * 256 + t;
  if (outF) outF[o] = y;
  if (outA) outA[o] = f2bf(y);
  if (outB) outB[o] = f2bf(y + addp[o]);
}

// ---------------------------------------------------------------- generic GEMM (small mats)
__global__ __launch_bounds__(256, 4) void gemm_kernel(
    const unsigned short* __restrict__ A, const unsigned short* __restrict__ W,
    const float* __restrict__ bias, const float* __restrict__ resid,
    float* __restrict__ Cf, unsigned short* __restrict__ Cb,
    int M, int N, int K, float alpha, int relu)
{
  __shared__ unsigned short As[64 * 64];
  __shared__ unsigned short Ws[64 * 64];
  const int tid = threadIdx.x;
  const int l = tid & 63;
  const int w = tid >> 6;
  const int wm = w >> 1, wn = w & 1;
  const int bm = blockIdx.x * 64, bn = blockIdx.y * 64;
  f32x4 acc[2][2] = {{{0,0,0,0},{0,0,0,0}},{{0,0,0,0},{0,0,0,0}}};

  for (int kc = 0; kc < K; kc += 64){
    __syncthreads();
    #pragma unroll
    for (int i = 0; i < 2; ++i){
      int idx = tid + i * 256;
      int r = idx >> 3, s = idx & 7;
      int byte = (s * 16) ^ ((r & 7) << 4);
      *(short8*)((char*)As + r * 128 + byte) = *(const short8*)(A + (size_t)(bm + r) * K + kc + s * 8);
      *(short8*)((char*)Ws + r * 128 + byte) = *(const short8*)(W + (size_t)(bn + r) * K + kc + s * 8);
    }
    __syncthreads();
    #pragma unroll
    for (int ks = 0; ks < 2; ++ks){
      short8 af[2], bf[2];
      af[0] = ldfrag(As, 128, wm * 32,      ks, l);
      af[1] = ldfrag(As, 128, wm * 32 + 16, ks, l);
      bf[0] = ldfrag(Ws, 128, wn * 32,      ks, l);
      bf[1] = ldfrag(Ws, 128, wn * 32 + 16, ks, l);
      #pragma unroll
      for (int i = 0; i < 2; ++i)
        #pragma unroll
        for (int j = 0; j < 2; ++j)
          acc[i][j] = mfma16(af[i], bf[j], acc[i][j]);
    }
  }
  #pragma unroll
  for (int i = 0; i < 2; ++i)
  #pragma unroll
  for (int j = 0; j < 2; ++j){
    int col = bn + wn * 32 + j * 16 + (l & 15);
    float bv = bias ? bias[col] : 0.f;
    #pragma unroll
    for (int u = 0; u < 4; ++u){
      int row = bm + wm * 32 + i * 16 + ((l >> 4) << 2) + u;
      float v = alpha * acc[i][j][u] + bv;
      if (relu) v = fmaxf(v, 0.f);
      if (resid) v += resid[(size_t)row * N + col];
      if (Cf) Cf[(size_t)row * N + col] = v;
      if (Cb) Cb[(size_t)row * N + col] = f2bf(v);
    }
  }
}

// ---------------------------------------------------------------- self-attention
__global__ __launch_bounds__(256) void attn_kernel(
    const float* __restrict__ qkp, const float* __restrict__ vp,
    unsigned short* __restrict__ attn_o)
{
  __shared__ float ks[128][33];
  __shared__ float vs[128][33];
  __shared__ float sc[128][129];
  const int bh = blockIdx.x;
  const int b = bh >> 3, h = bh & 7;
  const int tid = threadIdx.x;
  const int lrow = tid >> 1;
  const int half = tid & 1;
  {
    int s = tid >> 1;
    int d0 = half * 16;
    const float* kp = qkp + ((size_t)s * Bn + b) * 512 + 256 + h * 32 + d0;
    const float* vv = vp  + ((size_t)s * Bn + b) * 256 +       h * 32 + d0;
    #pragma unroll
    for (int d = 0; d < 16; d += 4){
      *(float4*)&ks[s][d0 + d] = *(const float4*)(kp + d);
      *(float4*)&vs[s][d0 + d] = *(const float4*)(vv + d);
    }
  }
  __syncthreads();
  float qv[32];
  const float* qp = qkp + ((size_t)lrow * Bn + b) * 512 + h * 32;
  #pragma unroll
  for (int d = 0; d < 32; ++d) qv[d] = qp[d];
  const float scale = 0.17677669529663687f;
  float mloc = -1e30f;
  for (int s2 = 0; s2 < 64; ++s2){
    int s = half * 64 + s2;
    float dot = 0.f;
    #pragma unroll
    for (int d = 0; d < 32; ++d) dot += qv[d] * ks[s][d];
    dot *= scale;
    sc[lrow][s] = dot;
    mloc = fmaxf(mloc, dot);
  }
  float m = fmaxf(mloc, __shfl_xor(mloc, 1, 64));
  float sum = 0.f;
  for (int s2 = 0; s2 < 64; ++s2){
    int s = half * 64 + s2;
    float e = __expf(sc[lrow][s] - m);
    sum += e;
    sc[lrow][s] = e;
  }
  sum += __shfl_xor(sum, 1, 64);
  float inv = 1.f / sum;
  float o[32];
  #pragma unroll
  for (int d = 0; d < 32; ++d) o[d] = 0.f;
  for (int s2 = 0; s2 < 64; ++s2){
    int s = half * 64 + s2;
    float e = sc[lrow][s];
    #pragma unroll
    for (int d = 0; d < 32; ++d) o[d] += e * vs[s][d];
  }
  #pragma unroll
  for (int d = 0; d < 32; ++d){
    o[d] += __shfl_xor(o[d], 1, 64);
    o[d] *= inv;
  }
  unsigned short* op = attn_o + ((size_t)lrow * Bn + b) * 256 + h * 32 + half * 16;
  #pragma unroll
  for (int d = 0; d < 16; ++d) op[d] = f2bf(o[half * 16 + d]);
}

// ---------------------------------------------------------------- fused relation branch
// One block per qb, 1024 threads = 16 waves; wave w owns f-slice [16w, 16w+16).
// Weight f-slices in regs (96 VGPR total); __launch_bounds__(1024,4) grants the
// 128-VGPR cap (4 waves/EU, 1 block/CU) so they are NOT spilled (R9 lesson).
// rel (f32) + mem (bf16) staged via global_load_lds, double-buffered, counted vmcnt(3).
// Per 32-c tile: convert -> x,y (bf16 swizzled LDS); phase1 h=relu(x@W1+b1) -> hb;
// phase2 e=exp((h@W2)/16), acc += e*(y@Wv). b2 cancels; vb in epilogue.
__global__ __launch_bounds__(1024, 4) void relfused_kernel(
    const float* __restrict__ rel, const unsigned short* __restrict__ mem_bf,
    const float* __restrict__ t22f,
    const unsigned short* __restrict__ W1g,
    const unsigned short* __restrict__ W2g,
    const unsigned short* __restrict__ Wvg,
    const float* __restrict__ b1,
    const float* __restrict__ vbp,
    unsigned short* __restrict__ trel)
{
  __shared__ char relbuf[2 * 32768];   // 64 KB: f32 tile, [32 rows][1024 B], dbuf
  __shared__ char membuf[2 * 16384];   // 32 KB: bf16 tile, [32 rows][512 B], dbuf
  __shared__ char xb[16384];           // 16 KB: bf16 [32 rows][512 B] swizzled
  __shared__ char yb[16384];
  __shared__ char hb[16384];
  __shared__ float t2s[256];
  __shared__ float b1s[256];

  const int qb = blockIdx.x;
  const int q = qb >> 2, b = qb & 3;
  const int tid = threadIdx.x;
  const int w = tid >> 6, l = tid & 63;
  const int l15 = l & 15, lg = l >> 4;

  if (tid < 256){ t2s[tid] = t22f[(size_t)qb * 256 + tid]; b1s[tid] = b1[tid]; }

  // ---- weight f-slice fragments -> regs (3 x 8 short8 = 96 VGPR)
  short8 w1r[8], w2r[8], wvr[8];
  {
    const size_t F = (size_t)(w * 16 + l15);
    #pragma unroll
    for (int kc = 0; kc < 8; ++kc){
      size_t byte = F * 512 + (size_t)((kc * 64 + lg * 16) ^ (l15 << 4));
      w1r[kc] = *(const short8*)((const char*)W1g + byte);
      w2r[kc] = *(const short8*)((const char*)W2g + byte);
      wvr[kc] = *(const short8*)((const char*)Wvg + byte);
    }
  }

  // ---- async staging: 3 gload_lds per wave per tile
  auto issue = [&](int tp){
    const int p = tp & 1;
    const int c0 = tp * 32;
    #pragma unroll
    for (int i = 0; i < 2; ++i){
      int c = c0 + 2 * w + i;
      gload_lds16(rel + (((size_t)q * 512 + c) * 4 + b) * 256 + l * 4,
                  relbuf + p * 32768 + (2 * w + i) * 1024);
    }
    int c = c0 + 2 * w + (l >> 5);
    gload_lds16(mem_bf + ((size_t)(c * 4 + b)) * 256 + (l & 31) * 8,
                membuf + p * 16384 + w * 1024);
  };

  float ta[4] = {0.f, 0.f, 0.f, 0.f}, la[4] = {0.f, 0.f, 0.f, 0.f};

  issue(0);

  for (int t = 0; t < 16; ++t){
    if (t < 15){
      issue(t + 1);
      asm volatile("s_waitcnt vmcnt(3)" ::: "memory");
    } else {
      asm volatile("s_waitcnt vmcnt(0)" ::: "memory");
    }
    __builtin_amdgcn_sched_barrier(0);
    __syncthreads();                       // tile-t staged everywhere; prev phase2 done

    // ---- convert: relbuf+membuf+t2 -> xb (x = t2 - m + r), yb (y = r + m)
    {
      const int cr = tid >> 5, d8 = tid & 31;
      const char* rbp = relbuf + (t & 1) * 32768 + cr * 1024;
      const char* mbp = membuf + (t & 1) * 16384 + cr * 512;
      int swz = (cr & 15) << 4;
      int bo1 = cr * 512 + ((((d8 >> 1) * 16) ^ swz) | ((d8 & 1) * 8));
      int bo2 = cr * 512 + ((((16 + (d8 >> 1)) * 16) ^ swz) | ((d8 & 1) * 8));
      {
        float4 ra = *(const float4*)(rbp + d8 * 16);
        uint2  ma = *(const uint2*)(mbp + d8 * 8);
        float4 t4 = *(const float4*)((const char*)t2s + d8 * 16);
        float m0 = bfl(ma.x), m1 = bfh(ma.x), m2 = bfl(ma.y), m3 = bfh(ma.y);
        uint2 xw, yw;
        xw.x = pk2(t4.x - m0 + ra.x, t4.y - m1 + ra.y);
        xw.y = pk2(t4.z - m2 + ra.z, t4.w - m3 + ra.w);
        yw.x = pk2(ra.x + m0, ra.y + m1);
        yw.y = pk2(ra.z + m2, ra.w + m3);
        *(uint2*)(xb + bo1) = xw;
        *(uint2*)(yb + bo1) = yw;
      }
      {
        float4 ra = *(const float4*)(rbp + 512 + d8 * 16);
        uint2  ma = *(const uint2*)(mbp + 256 + d8 * 8);
        float4 t4 = *(const float4*)((const char*)t2s + 512 + d8 * 16);
        float m0 = bfl(ma.x), m1 = bfh(ma.x), m2 = bfl(ma.y), m3 = bfh(ma.y);
        uint2 xw, yw;
        xw.x = pk2(t4.x - m0 + ra.x, t4.y - m1 + ra.y);
        xw.y = pk2(t4.z - m2 + ra.z, t4.w - m3 + ra.w);
        yw.x = pk2(ra.x + m0, ra.y + m1);
        yw.y = pk2(ra.z + m2, ra.w + m3);
        *(uint2*)(xb + bo2) = xw;
        *(uint2*)(yb + bo2) = yw;
      }
    }
    __syncthreads();                       // xb, yb ready

    // ---- phase1: h = relu(x@W1 + b1) -> hb
    #pragma unroll
    for (int cs = 0; cs < 2; ++cs){
      f32x4 acc = {0.f, 0.f, 0.f, 0.f};
      const char* xrow = xb + (cs * 16 + l15) * 512;
      #pragma unroll
      for (int kc = 0; kc < 8; ++kc)
        acc = mfma16(w1r[kc], *(const short8*)(xrow + ((kc * 64 + lg * 16) ^ (l15 << 4))), acc);
      float4 bb = *(const float4*)&b1s[w * 16 + lg * 4];
      uint2 hp;
      hp.x = pk2(fmaxf(acc[0] + bb.x, 0.f), fmaxf(acc[1] + bb.y, 0.f));
      hp.y = pk2(fmaxf(acc[2] + bb.z, 0.f), fmaxf(acc[3] + bb.w, 0.f));
      int ro = w * 32 + lg * 8;
      *(uint2*)(hb + (cs * 16 + l15) * 512 + (((ro & ~15) ^ (l15 << 4)) | (ro & 8))) = hp;
    }
    __syncthreads();                       // hb ready

    // ---- phase2: sim-GEMM (W2) + v2-GEMM (Wv) + exp accumulate
    #pragma unroll
    for (int cs = 0; cs < 2; ++cs){
      f32x4 as = {0.f, 0.f, 0.f, 0.f}, av = {0.f, 0.f, 0.f, 0.f};
      const char* hrow = hb + (cs * 16 + l15) * 512;
      const char* yrow = yb + (cs * 16 + l15) * 512;
      #pragma unroll
      for (int kc = 0; kc < 8; ++kc){
        int off = (kc * 64 + lg * 16) ^ (l15 << 4);
        as = mfma16(w2r[kc], *(const short8*)(hrow + off), as);
        av = mfma16(wvr[kc], *(const short8*)(yrow + off), av);
      }
      #pragma unroll
      for (int u = 0; u < 4; ++u){
        float e = __expf(as[u] * 0.0625f);
        ta[u] += e * av[u];
        la[u] += e;
      }
    }
  }

  // ---- reduce over the 16 c-lanes, add vb, write out
  #pragma unroll
  for (int u = 0; u < 4; ++u){
    #pragma unroll
    for (int m = 1; m <= 8; m <<= 1){
      ta[u] += __shfl_xor(ta[u], m, 64);
      la[u] += __shfl_xor(la[u], m, 64);
    }
  }
  if (l15 == 0){
    float4 vb4 = *(const float4*)(vbp + w * 16 + lg * 4);
    uint2 o;
    o.x = pk2(ta[0] / la[0] + vb4.x, ta[1] / la[1] + vb4.y);
    o.y = pk2(ta[2] / la[2] + vb4.z, ta[3] / la[3] + vb4.w);
    *(uint2*)(trel + (size_t)qb * 256 + w * 16 + lg * 4) = o;
  }
}

// ---------------------------------------------------------------- launch
extern "C" void kernel_launch(void* const* d_in, const int* in_sizes, int n_in,
                              void* d_out, int out_size, void* d_ws, size_t ws_size,
                              hipStream_t stream)
{
  const float* tgt  = (const float*)d_in[0];
  const float* mem  = (const float*)d_in[1];
  const float* qpos = (const float*)d_in[2];
  const float* rel  = (const float*)d_in[3];
  const float* ln1g = (const float*)d_in[4];
  const float* ln1b = (const float*)d_in[5];
  const float* ln2g = (const float*)d_in[6];
  const float* ln2b = (const float*)d_in[7];
  const float* ln3g = (const float*)d_in[8];
  const float* ln3b = (const float*)d_in[9];
  const float* inw  = (const float*)d_in[10];
  const float* inb  = (const float*)d_in[11];
  const float* aow  = (const float*)d_in[12];
  const float* aob  = (const float*)d_in[13];
  const float* m1w  = (const float*)d_in[14];
  const float* m1b  = (const float*)d_in[15];
  const float* m2w  = (const float*)d_in[16];
  const float* m2b  = (const float*)d_in[17];
  const float* vw   = (const float*)d_in[18];
  const float* vb   = (const float*)d_in[19];
  const float* ow   = (const float*)d_in[20];
  const float* ob   = (const float*)d_in[21];
  const float* f1w  = (const float*)d_in[22];
  const float* f1b  = (const float*)d_in[23];
  const float* f2w  = (const float*)d_in[24];
  const float* f2b  = (const float*)d_in[25];

  char* ws = (char*)d_ws;
  size_t off = 0;
  auto alloc = [&](size_t bytes) -> char* {
    char* p = ws + off; off += (bytes + 255) & ~size_t(255); return p;
  };
  unsigned short* w1pk    = (unsigned short*)alloc(256 * 256 * 2);
  unsigned short* w2pk    = (unsigned short*)alloc(256 * 256 * 2);
  unsigned short* wvpk    = (unsigned short*)alloc(256 * 256 * 2);
  unsigned short* mem_bf  = (unsigned short*)alloc(2048 * 256 * 2);
  unsigned short* inw_bf  = (unsigned short*)alloc(768 * 256 * 2);
  unsigned short* aow_bf  = (unsigned short*)alloc(256 * 256 * 2);
  unsigned short* ow_bf   = (unsigned short*)alloc(256 * 256 * 2);
  unsigned short* f1w_bf  = (unsigned short*)alloc(1024 * 256 * 2);
  unsigned short* f2w_bf  = (unsigned short*)alloc(256 * 1024 * 2);
  unsigned short* t21_bf  = (unsigned short*)alloc(512 * 256 * 2);
  unsigned short* qk_bf   = (unsigned short*)alloc(512 * 256 * 2);
  float*          qkp     = (float*)alloc(512 * 512 * 4);
  float*          vp      = (float*)alloc(512 * 256 * 4);
  unsigned short* ao_bf   = (unsigned short*)alloc(512 * 256 * 2);
  float*          tgta    = (float*)alloc(512 * 256 * 4);
  float*          t22_f   = (float*)alloc(512 * 256 * 4);
  unsigned short* trel_bf = (unsigned short*)alloc(512 * 256 * 2);
  float*          tgtr    = (float*)alloc(512 * 256 * 4);
  unsigned short* t23_bf  = (unsigned short*)alloc(512 * 256 * 2);
  unsigned short* ffh_bf  = (unsigned short*)alloc(512 * 1024 * 2);

  conv_all_kernel<<<2048, 256, 0, stream>>>(inw, inw_bf, aow, aow_bf, ow, ow_bf,
      f1w, f1w_bf, f2w, f2w_bf, m1w, w1pk, m2w, w2pk, vw, wvpk, mem, mem_bf);

  // ln1 -> tgt2_1 (bf16), qk = tgt2_1 + query_pos (bf16)
  ln_kernel<<<512, 256, 0, stream>>>(tgt, ln1g, ln1b, qpos, nullptr, t21_bf, qk_bf);

  // q|k projection (N=512) and v projection (N=256)
  gemm_kernel<<<dim3(8, 8), 256, 0, stream>>>(qk_bf, inw_bf, inb, nullptr,
      qkp, nullptr, 512, 512, 256, 1.f, 0);
  gemm_kernel<<<dim3(8, 4), 256, 0, stream>>>(t21_bf, inw_bf + 512 * 256, inb + 512, nullptr,
      vp, nullptr, 512, 256, 256, 1.f, 0);

  attn_kernel<<<32, 256, 0, stream>>>(qkp, vp, ao_bf);

  // out-proj + residual tgt -> tgta
  gemm_kernel<<<dim3(8, 4), 256, 0, stream>>>(ao_bf, aow_bf, aob, tgt,
      tgta, nullptr, 512, 256, 256, 1.f, 0);

  // ln2 -> t22 (f32)
  ln_kernel<<<512, 256, 0, stream>>>(tgta, ln2g, ln2b, nullptr, t22_f, nullptr, nullptr);

  // fused relation branch
  relfused_kernel<<<512, 1024, 0, stream>>>(rel, mem_bf, t22_f, w1pk, w2pk, wvpk,
      m1b, vb, trel_bf);

  // t = relu(t@o_w + o_b) + t22
  gemm_kernel<<<dim3(8, 4), 256, 0, stream>>>(trel_bf, ow_bf, ob, t22_f,
      tgtr, nullptr, 512, 256, 256, 1.f, 1);

  // ln3 -> bf16
  ln_kernel<<<512, 256, 0, stream>>>(tgtr, ln3g, ln3b, nullptr, nullptr, t23_bf, nullptr);

  // ffn
  gemm_kernel<<<dim3(8, 16), 256, 0, stream>>>(t23_bf, f1w_bf, f1b, nullptr,
      nullptr, ffh_bf, 512, 1024, 256, 1.f, 1);
  gemm_kernel<<<dim3(8, 4), 256, 0, stream>>>(ffh_bf, f2w_bf, f2b, tgtr,
      (float*)d_out, nullptr, 512, 256, 1024, 1.f, 0);
}

// Round 11
// 392.624 us; speedup vs baseline: 1.5492x; 1.5492x over previous
//
#include <hip/hip_runtime.h>
#include <hip/hip_bf16.h>
#include <cstdint>
#include <cstddef>

#define DEV __device__ __forceinline__

typedef __attribute__((ext_vector_type(8))) short short8;
typedef __attribute__((ext_vector_type(4))) float f32x4;

constexpr int Dm  = 256;
constexpr int Qn  = 128;
constexpr int Cn  = 512;
constexpr int Bn  = 4;

DEV unsigned short f2bf(float f){
  unsigned int u = __builtin_bit_cast(unsigned int, f);
  u += 0x7fffu + ((u >> 16) & 1u);
  return (unsigned short)(u >> 16);
}
DEV float bfl(unsigned int u){ return __builtin_bit_cast(float, u << 16); }
DEV float bfh(unsigned int u){ return __builtin_bit_cast(float, u & 0xffff0000u); }
DEV unsigned int pk2(float a, float b){
  return (unsigned int)f2bf(a) | ((unsigned int)f2bf(b) << 16);
}

DEV f32x4 mfma16(short8 a, short8 b, f32x4 c){
  return __builtin_amdgcn_mfma_f32_16x16x32_bf16(a, b, c, 0, 0, 0);
}

// 16x16x32 fragment load from XOR-swizzled LDS tile (rowbytes bytes/row) — for gemm_kernel
DEV short8 ldfrag(const unsigned short* buf, int rowbytes, int row0, int ks, int l){
  int r = row0 + (l & 15);
  int byte = (ks * 64 + ((l >> 4) * 16)) ^ ((r & 7) << 4);
  return *(const short8*)((const char*)buf + r * rowbytes + byte);
}

// async global->LDS, 16B/lane; LDS dest = wave-uniform base (HW adds lane*16)
DEV void gload_lds16(const void* g, void* lds){
  __builtin_amdgcn_global_load_lds(
      (const __attribute__((address_space(1))) unsigned int*)g,
      (__attribute__((address_space(3))) unsigned int*)lds, 16, 0, 0);
}

// ---------------------------------------------------------------- converts + weight packs
// pack W[f][d] into the fragment image: byte f*512 + ((d8*16) ^ ((f&15)<<4))
DEV void packw(unsigned short* dst, const float* src, int j){
  int f = j >> 8, d = j & 255;
  int d8 = d >> 3, e = d & 7;
  int byte = (d8 * 16) ^ ((f & 15) << 4);
  dst[f * 256 + (byte >> 1) + e] = f2bf(src[j]);
}

__global__ __launch_bounds__(256) void conv_all_kernel(
    const float* inw, unsigned short* inw_bf,
    const float* aow, unsigned short* aow_bf,
    const float* ow,  unsigned short* ow_bf,
    const float* f1w, unsigned short* f1w_bf,
    const float* f2w, unsigned short* f2w_bf,
    const float* m1w, unsigned short* w1pk,
    const float* m2w, unsigned short* w2pk,
    const float* vw,  unsigned short* wvpk,
    const float* memp, unsigned short* mem_bf)
{
  const int total = 196608 + 65536 + 65536 + 262144 + 262144 + 3 * 65536 + 524288;
  for (int i = blockIdx.x * 256 + threadIdx.x; i < total; i += gridDim.x * 256){
    int j = i;
    if (j < 196608){ inw_bf[j] = f2bf(inw[j]); continue; } j -= 196608;
    if (j < 65536) { aow_bf[j] = f2bf(aow[j]); continue; } j -= 65536;
    if (j < 65536) { ow_bf[j]  = f2bf(ow[j]);  continue; } j -= 65536;
    if (j < 262144){ f1w_bf[j] = f2bf(f1w[j]); continue; } j -= 262144;
    if (j < 262144){ f2w_bf[j] = f2bf(f2w[j]); continue; } j -= 262144;
    if (j < 65536) { packw(w1pk, m1w, j); continue; } j -= 65536;
    if (j < 65536) { packw(w2pk, m2w, j); continue; } j -= 65536;
    if (j < 65536) { packw(wvpk, vw, j);  continue; } j -= 65536;
    mem_bf[j] = f2bf(memp[j]);
  }
}

// ---------------------------------------------------------------- layernorm
__global__ __launch_bounds__(256) void ln_kernel(
    const float* __restrict__ in, const float* __restrict__ g, const float* __restrict__ bt,
    const float* __restrict__ addp,
    float* __restrict__ outF, unsigned short* __restrict__ outA, unsigned short* __restrict__ outB)
{
  const int r = blockIdx.x, t = threadIdx.x;
  float x = in[(size_t)r * 256 + t];
  float s = x, s2 = x * x;
  #pragma unroll
  for (int m = 1; m < 64; m <<= 1){ s += __shfl_xor(s, m, 64); s2 += __shfl_xor(s2, m, 64); }
  __shared__ float ls[8];
  int w = t >> 6, l = t & 63;
  if (l == 0){ ls[w] = s; ls[4 + w] = s2; }
  __syncthreads();
  s  = ls[0] + ls[1] + ls[2] + ls[3];
  s2 = ls[4] + ls[5] + ls[6] + ls[7];
  float mean = s * (1.f / 256.f);
  float var  = s2 * (1.f / 256.f) - mean * mean;
  float y = (x - mean) * rsqrtf(var + 1e-5f) * g[t] + bt[t];
  size_t o = (size_t)r * 256 + t;
  if (outF) outF[o] = y;
  if (outA) outA[o] = f2bf(y);
  if (outB) outB[o] = f2bf(y + addp[o]);
}

// ---------------------------------------------------------------- generic GEMM (small mats)
__global__ __launch_bounds__(256, 4) void gemm_kernel(
    const unsigned short* __restrict__ A, const unsigned short* __restrict__ W,
    const float* __restrict__ bias, const float* __restrict__ resid,
    float* __restrict__ Cf, unsigned short* __restrict__ Cb,
    int M, int N, int K, float alpha, int relu)
{
  __shared__ unsigned short As[64 * 64];
  __shared__ unsigned short Ws[64 * 64];
  const int tid = threadIdx.x;
  const int l = tid & 63;
  const int w = tid >> 6;
  const int wm = w >> 1, wn = w & 1;
  const int bm = blockIdx.x * 64, bn = blockIdx.y * 64;
  f32x4 acc[2][2] = {{{0,0,0,0},{0,0,0,0}},{{0,0,0,0},{0,0,0,0}}};

  for (int kc = 0; kc < K; kc += 64){
    __syncthreads();
    #pragma unroll
    for (int i = 0; i < 2; ++i){
      int idx = tid + i * 256;
      int r = idx >> 3, s = idx & 7;
      int byte = (s * 16) ^ ((r & 7) << 4);
      *(short8*)((char*)As + r * 128 + byte) = *(const short8*)(A + (size_t)(bm + r) * K + kc + s * 8);
      *(short8*)((char*)Ws + r * 128 + byte) = *(const short8*)(W + (size_t)(bn + r) * K + kc + s * 8);
    }
    __syncthreads();
    #pragma unroll
    for (int ks = 0; ks < 2; ++ks){
      short8 af[2], bf[2];
      af[0] = ldfrag(As, 128, wm * 32,      ks, l);
      af[1] = ldfrag(As, 128, wm * 32 + 16, ks, l);
      bf[0] = ldfrag(Ws, 128, wn * 32,      ks, l);
      bf[1] = ldfrag(Ws, 128, wn * 32 + 16, ks, l);
      #pragma unroll
      for (int i = 0; i < 2; ++i)
        #pragma unroll
        for (int j = 0; j < 2; ++j)
          acc[i][j] = mfma16(af[i], bf[j], acc[i][j]);
    }
  }
  #pragma unroll
  for (int i = 0; i < 2; ++i)
  #pragma unroll
  for (int j = 0; j < 2; ++j){
    int col = bn + wn * 32 + j * 16 + (l & 15);
    float bv = bias ? bias[col] : 0.f;
    #pragma unroll
    for (int u = 0; u < 4; ++u){
      int row = bm + wm * 32 + i * 16 + ((l >> 4) << 2) + u;
      float v = alpha * acc[i][j][u] + bv;
      if (relu) v = fmaxf(v, 0.f);
      if (resid) v += resid[(size_t)row * N + col];
      if (Cf) Cf[(size_t)row * N + col] = v;
      if (Cb) Cb[(size_t)row * N + col] = f2bf(v);
    }
  }
}

// ---------------------------------------------------------------- self-attention
__global__ __launch_bounds__(256) void attn_kernel(
    const float* __restrict__ qkp, const float* __restrict__ vp,
    unsigned short* __restrict__ attn_o)
{
  __shared__ float ks[128][33];
  __shared__ float vs[128][33];
  __shared__ float sc[128][129];
  const int bh = blockIdx.x;
  const int b = bh >> 3, h = bh & 7;
  const int tid = threadIdx.x;
  const int lrow = tid >> 1;
  const int half = tid & 1;
  {
    int s = tid >> 1;
    int d0 = half * 16;
    const float* kp = qkp + ((size_t)s * Bn + b) * 512 + 256 + h * 32 + d0;
    const float* vv = vp  + ((size_t)s * Bn + b) * 256 +       h * 32 + d0;
    #pragma unroll
    for (int d = 0; d < 16; d += 4){
      *(float4*)&ks[s][d0 + d] = *(const float4*)(kp + d);
      *(float4*)&vs[s][d0 + d] = *(const float4*)(vv + d);
    }
  }
  __syncthreads();
  float qv[32];
  const float* qp = qkp + ((size_t)lrow * Bn + b) * 512 + h * 32;
  #pragma unroll
  for (int d = 0; d < 32; ++d) qv[d] = qp[d];
  const float scale = 0.17677669529663687f;
  float mloc = -1e30f;
  for (int s2 = 0; s2 < 64; ++s2){
    int s = half * 64 + s2;
    float dot = 0.f;
    #pragma unroll
    for (int d = 0; d < 32; ++d) dot += qv[d] * ks[s][d];
    dot *= scale;
    sc[lrow][s] = dot;
    mloc = fmaxf(mloc, dot);
  }
  float m = fmaxf(mloc, __shfl_xor(mloc, 1, 64));
  float sum = 0.f;
  for (int s2 = 0; s2 < 64; ++s2){
    int s = half * 64 + s2;
    float e = __expf(sc[lrow][s] - m);
    sum += e;
    sc[lrow][s] = e;
  }
  sum += __shfl_xor(sum, 1, 64);
  float inv = 1.f / sum;
  float o[32];
  #pragma unroll
  for (int d = 0; d < 32; ++d) o[d] = 0.f;
  for (int s2 = 0; s2 < 64; ++s2){
    int s = half * 64 + s2;
    float e = sc[lrow][s];
    #pragma unroll
    for (int d = 0; d < 32; ++d) o[d] += e * vs[s][d];
  }
  #pragma unroll
  for (int d = 0; d < 32; ++d){
    o[d] += __shfl_xor(o[d], 1, 64);
    o[d] *= inv;
  }
  unsigned short* op = attn_o + ((size_t)lrow * Bn + b) * 256 + h * 32 + half * 16;
  #pragma unroll
  for (int d = 0; d < 16; ++d) op[d] = f2bf(o[half * 16 + d]);
}

// ---------------------------------------------------------------- fused relation branch
// One block per qb, 512 threads = 8 waves; wave w owns f-slice [32w, 32w+32) (j=0,1).
// All three weight f-slices in regs (192/thread); (512,2) grants the 256-reg budget
// (R8-proven no-spill). rel(f32)+mem(bf16) staged via global_load_lds, double-buffered,
// counted vmcnt(6), issued one tile ahead (R9-proven staging).
// Per 32-c tile: convert (lane-linear reads, conflict-free) -> xb,yb (bf16 swizzled);
// phase1 h=relu(x@W1+b1) -> hb; phase2 e=exp((h@W2)/16), acc += e*(y@Wv).
// b2 cancels in ta/la ratio; vb added in epilogue.
__global__ __launch_bounds__(512, 2) void relfused_kernel(
    const float* __restrict__ rel, const unsigned short* __restrict__ mem_bf,
    const float* __restrict__ t22f,
    const unsigned short* __restrict__ W1g,
    const unsigned short* __restrict__ W2g,
    const unsigned short* __restrict__ Wvg,
    const float* __restrict__ b1,
    const float* __restrict__ vbp,
    unsigned short* __restrict__ trel)
{
  __shared__ char relbuf[2 * 32768];   // 64 KB: f32 tile, [32 rows][1024 B], dbuf
  __shared__ char membuf[2 * 16384];   // 32 KB: bf16 tile, [32 rows][512 B], dbuf
  __shared__ char xb[16384];           // 16 KB: bf16 [32 rows][512 B] swizzled
  __shared__ char yb[16384];
  __shared__ char hb[16384];
  __shared__ float t2s[256];
  __shared__ float b1s[256];

  const int qb = blockIdx.x;
  const int q = qb >> 2, b = qb & 3;
  const int tid = threadIdx.x;
  const int w = tid >> 6, l = tid & 63;
  const int l15 = l & 15, lg = l >> 4;

  if (tid < 256){ t2s[tid] = t22f[(size_t)qb * 256 + tid]; b1s[tid] = b1[tid]; }

  // ---- weight f-slice fragments -> regs (3 x 2 x 8 short8 = 192 regs, AGPR-backed)
  short8 w1r[2][8], w2r[2][8], wvr[2][8];
  #pragma unroll
  for (int j = 0; j < 2; ++j){
    const size_t F = (size_t)(w * 32 + j * 16 + l15);
    #pragma unroll
    for (int kc = 0; kc < 8; ++kc){
      size_t byte = F * 512 + (size_t)((kc * 64 + lg * 16) ^ (l15 << 4));
      w1r[j][kc] = *(const short8*)((const char*)W1g + byte);
      w2r[j][kc] = *(const short8*)((const char*)W2g + byte);
      wvr[j][kc] = *(const short8*)((const char*)Wvg + byte);
    }
  }

  // ---- async staging: 6 gload_lds per wave per tile (rel 4 + mem 2)
  auto issue = [&](int tp){
    const int p = tp & 1;
    const int c0 = tp * 32;
    #pragma unroll
    for (int i = 0; i < 4; ++i){
      int c = c0 + 4 * w + i;
      gload_lds16(rel + (((size_t)q * 512 + c) * 4 + b) * 256 + l * 4,
                  relbuf + p * 32768 + (4 * w + i) * 1024);
    }
    #pragma unroll
    for (int i = 0; i < 2; ++i){
      int c = c0 + 4 * w + 2 * i + (l >> 5);
      gload_lds16(mem_bf + ((size_t)(c * 4 + b)) * 256 + (l & 31) * 8,
                  membuf + p * 16384 + (4 * w + 2 * i) * 512);
    }
  };

  float ta[2][4], la[2][4];
  #pragma unroll
  for (int j = 0; j < 2; ++j)
    #pragma unroll
    for (int u = 0; u < 4; ++u){ ta[j][u] = 0.f; la[j][u] = 0.f; }

  issue(0);

  for (int t = 0; t < 16; ++t){
    if (t < 15){
      issue(t + 1);
      asm volatile("s_waitcnt vmcnt(6)" ::: "memory");
    } else {
      asm volatile("s_waitcnt vmcnt(0)" ::: "memory");
    }
    __builtin_amdgcn_sched_barrier(0);
    __syncthreads();              // tile-t staged everywhere; prev phase2 reads done

    // ---- convert: lane-linear sweeps (conflict-free). Sweep s: row = 8s + w,
    // lane covers f32 d in [l*4, l*4+4). Writes 8B each to xb (x=t2-m+r), yb (y=r+m).
    {
      const char* rbase = relbuf + (t & 1) * 32768;
      const char* mbase = membuf + (t & 1) * 16384;
      #pragma unroll
      for (int s = 0; s < 4; ++s){
        int row = 8 * s + w;
        float4 ra = *(const float4*)(rbase + row * 1024 + l * 16);
        uint2  ma = *(const uint2*)(mbase + row * 512 + l * 8);
        float4 t4 = *(const float4*)(t2s + l * 4);
        float m0 = bfl(ma.x), m1 = bfh(ma.x), m2 = bfl(ma.y), m3 = bfh(ma.y);
        uint2 xw, yw;
        xw.x = pk2(t4.x - m0 + ra.x, t4.y - m1 + ra.y);
        xw.y = pk2(t4.z - m2 + ra.z, t4.w - m3 + ra.w);
        yw.x = pk2(ra.x + m0, ra.y + m1);
        yw.y = pk2(ra.z + m2, ra.w + m3);
        int byte = row * 512 + ((((l >> 1) * 16) ^ ((row & 15) << 4)) | ((l & 1) * 8));
        *(uint2*)(xb + byte) = xw;
        *(uint2*)(yb + byte) = yw;
      }
    }
    __syncthreads();              // xb, yb ready

    // ---- phase1: h = relu(x@W1 + b1) -> hb
    #pragma unroll
    for (int cs = 0; cs < 2; ++cs){
      f32x4 acc[2] = {{0,0,0,0},{0,0,0,0}};
      const char* xrow = xb + (cs * 16 + l15) * 512;
      #pragma unroll
      for (int kc = 0; kc < 8; ++kc){
        short8 bx = *(const short8*)(xrow + ((kc * 64 + lg * 16) ^ (l15 << 4)));
        acc[0] = mfma16(w1r[0][kc], bx, acc[0]);
        acc[1] = mfma16(w1r[1][kc], bx, acc[1]);
      }
      #pragma unroll
      for (int j = 0; j < 2; ++j){
        float4 bb = *(const float4*)&b1s[w * 32 + j * 16 + lg * 4];
        uint2 hp;
        hp.x = pk2(fmaxf(acc[j][0] + bb.x, 0.f), fmaxf(acc[j][1] + bb.y, 0.f));
        hp.y = pk2(fmaxf(acc[j][2] + bb.z, 0.f), fmaxf(acc[j][3] + bb.w, 0.f));
        int ro = w * 64 + j * 32 + lg * 8;
        *(uint2*)(hb + (cs * 16 + l15) * 512 + (((ro & ~15) ^ (l15 << 4)) | (ro & 8))) = hp;
      }
    }
    __syncthreads();              // hb ready

    // ---- phase2: sim-GEMM (W2) + v2-GEMM (Wv) + exp accumulate
    #pragma unroll
    for (int cs = 0; cs < 2; ++cs){
      f32x4 as[2] = {{0,0,0,0},{0,0,0,0}};
      f32x4 av[2] = {{0,0,0,0},{0,0,0,0}};
      const char* hrow = hb + (cs * 16 + l15) * 512;
      const char* yrow = yb + (cs * 16 + l15) * 512;
      #pragma unroll
      for (int kc = 0; kc < 8; ++kc){
        int off = (kc * 64 + lg * 16) ^ (l15 << 4);
        short8 bh = *(const short8*)(hrow + off);
        short8 by = *(const short8*)(yrow + off);
        as[0] = mfma16(w2r[0][kc], bh, as[0]);
        as[1] = mfma16(w2r[1][kc], bh, as[1]);
        av[0] = mfma16(wvr[0][kc], by, av[0]);
        av[1] = mfma16(wvr[1][kc], by, av[1]);
      }
      #pragma unroll
      for (int j = 0; j < 2; ++j)
        #pragma unroll
        for (int u = 0; u < 4; ++u){
          float e = __expf(as[j][u] * 0.0625f);
          ta[j][u] += e * av[j][u];
          la[j][u] += e;
        }
    }
  }

  // ---- reduce over the 16 c-lanes, add vb, write out
  #pragma unroll
  for (int j = 0; j < 2; ++j)
    #pragma unroll
    for (int u = 0; u < 4; ++u){
      #pragma unroll
      for (int m = 1; m <= 8; m <<= 1){
        ta[j][u] += __shfl_xor(ta[j][u], m, 64);
        la[j][u] += __shfl_xor(la[j][u], m, 64);
      }
    }
  if (l15 == 0){
    #pragma unroll
    for (int j = 0; j < 2; ++j){
      float4 vb4 = *(const float4*)(vbp + w * 32 + j * 16 + lg * 4);
      uint2 o;
      o.x = pk2(ta[j][0] / la[j][0] + vb4.x, ta[j][1] / la[j][1] + vb4.y);
      o.y = pk2(ta[j][2] / la[j][2] + vb4.z, ta[j][3] / la[j][3] + vb4.w);
      *(uint2*)(trel + (size_t)qb * 256 + w * 32 + j * 16 + lg * 4) = o;
    }
  }
}

// ---------------------------------------------------------------- launch
extern "C" void kernel_launch(void* const* d_in, const int* in_sizes, int n_in,
                              void* d_out, int out_size, void* d_ws, size_t ws_size,
                              hipStream_t stream)
{
  const float* tgt  = (const float*)d_in[0];
  const float* mem  = (const float*)d_in[1];
  const float* qpos = (const float*)d_in[2];
  const float* rel  = (const float*)d_in[3];
  const float* ln1g = (const float*)d_in[4];
  const float* ln1b = (const float*)d_in[5];
  const float* ln2g = (const float*)d_in[6];
  const float* ln2b = (const float*)d_in[7];
  const float* ln3g = (const float*)d_in[8];
  const float* ln3b = (const float*)d_in[9];
  const float* inw  = (const float*)d_in[10];
  const float* inb  = (const float*)d_in[11];
  const float* aow  = (const float*)d_in[12];
  const float* aob  = (const float*)d_in[13];
  const float* m1w  = (const float*)d_in[14];
  const float* m1b  = (const float*)d_in[15];
  const float* m2w  = (const float*)d_in[16];
  const float* m2b  = (const float*)d_in[17];
  const float* vw   = (const float*)d_in[18];
  const float* vb   = (const float*)d_in[19];
  const float* ow   = (const float*)d_in[20];
  const float* ob   = (const float*)d_in[21];
  const float* f1w  = (const float*)d_in[22];
  const float* f1b  = (const float*)d_in[23];
  const float* f2w  = (const float*)d_in[24];
  const float* f2b  = (const float*)d_in[25];

  char* ws = (char*)d_ws;
  size_t off = 0;
  auto alloc = [&](size_t bytes) -> char* {
    char* p = ws + off; off += (bytes + 255) & ~size_t(255); return p;
  };
  unsigned short* w1pk    = (unsigned short*)alloc(256 * 256 * 2);
  unsigned short* w2pk    = (unsigned short*)alloc(256 * 256 * 2);
  unsigned short* wvpk    = (unsigned short*)alloc(256 * 256 * 2);
  unsigned short* mem_bf  = (unsigned short*)alloc(2048 * 256 * 2);
  unsigned short* inw_bf  = (unsigned short*)alloc(768 * 256 * 2);
  unsigned short* aow_bf  = (unsigned short*)alloc(256 * 256 * 2);
  unsigned short* ow_bf   = (unsigned short*)alloc(256 * 256 * 2);
  unsigned short* f1w_bf  = (unsigned short*)alloc(1024 * 256 * 2);
  unsigned short* f2w_bf  = (unsigned short*)alloc(256 * 1024 * 2);
  unsigned short* t21_bf  = (unsigned short*)alloc(512 * 256 * 2);
  unsigned short* qk_bf   = (unsigned short*)alloc(512 * 256 * 2);
  float*          qkp     = (float*)alloc(512 * 512 * 4);
  float*          vp      = (float*)alloc(512 * 256 * 4);
  unsigned short* ao_bf   = (unsigned short*)alloc(512 * 256 * 2);
  float*          tgta    = (float*)alloc(512 * 256 * 4);
  float*          t22_f   = (float*)alloc(512 * 256 * 4);
  unsigned short* trel_bf = (unsigned short*)alloc(512 * 256 * 2);
  float*          tgtr    = (float*)alloc(512 * 256 * 4);
  unsigned short* t23_bf  = (unsigned short*)alloc(512 * 256 * 2);
  unsigned short* ffh_bf  = (unsigned short*)alloc(512 * 1024 * 2);

  conv_all_kernel<<<2048, 256, 0, stream>>>(inw, inw_bf, aow, aow_bf, ow, ow_bf,
      f1w, f1w_bf, f2w, f2w_bf, m1w, w1pk, m2w, w2pk, vw, wvpk, mem, mem_bf);

  // ln1 -> tgt2_1 (bf16), qk = tgt2_1 + query_pos (bf16)
  ln_kernel<<<512, 256, 0, stream>>>(tgt, ln1g, ln1b, qpos, nullptr, t21_bf, qk_bf);

  // q|k projection (N=512) and v projection (N=256)
  gemm_kernel<<<dim3(8, 8), 256, 0, stream>>>(qk_bf, inw_bf, inb, nullptr,
      qkp, nullptr, 512, 512, 256, 1.f, 0);
  gemm_kernel<<<dim3(8, 4), 256, 0, stream>>>(t21_bf, inw_bf + 512 * 256, inb + 512, nullptr,
      vp, nullptr, 512, 256, 256, 1.f, 0);

  attn_kernel<<<32, 256, 0, stream>>>(qkp, vp, ao_bf);

  // out-proj + residual tgt -> tgta
  gemm_kernel<<<dim3(8, 4), 256, 0, stream>>>(ao_bf, aow_bf, aob, tgt,
      tgta, nullptr, 512, 256, 256, 1.f, 0);

  // ln2 -> t22 (f32)
  ln_kernel<<<512, 256, 0, stream>>>(tgta, ln2g, ln2b, nullptr, t22_f, nullptr, nullptr);

  // fused relation branch
  relfused_kernel<<<512, 512, 0, stream>>>(rel, mem_bf, t22_f, w1pk, w2pk, wvpk,
      m1b, vb, trel_bf);

  // t = relu(t@o_w + o_b) + t22
  gemm_kernel<<<dim3(8, 4), 256, 0, stream>>>(trel_bf, ow_bf, ob, t22_f,
      tgtr, nullptr, 512, 256, 256, 1.f, 1);

  // ln3 -> bf16
  ln_kernel<<<512, 256, 0, stream>>>(tgtr, ln3g, ln3b, nullptr, nullptr, t23_bf, nullptr);

  // ffn
  gemm_kernel<<<dim3(8, 16), 256, 0, stream>>>(t23_bf, f1w_bf, f1b, nullptr,
      nullptr, ffh_bf, 512, 1024, 256, 1.f, 1);
  gemm_kernel<<<dim3(8, 4), 256, 0, stream>>>(ffh_bf, f2w_bf, f2b, tgtr,
      (float*)d_out, nullptr, 512, 256, 1024, 1.f, 0);
}